// Round 2
// baseline (406.789 us; speedup 1.0000x reference)
//
#include <hip/hip_runtime.h>

#define N_NODES 50000
#define N_EDGES 800000
#define NE4 (N_EDGES / 4)
#define NMASKW 1568          // ceil(50000/32)=1563, padded
#define MAXN1 192            // LDS accumulator rows (deg(node1)~16)
#define GRID 512             // co-resident: LDS allows 3 blocks/CU, launch_bounds caps VGPR for 2/CU
#define TPB 256

__device__ __forceinline__ float lrelu(float v) { return v >= 0.f ? v : 0.01f * v; }
__device__ __forceinline__ bool mtest(const unsigned int* m, int i) {
    return (m[i >> 5] >> (i & 31)) & 1u;
}

struct Params {
    const float* x; const int* src; const int* dst;
    const float* W0; const float* b0; const float* W1; const float* b1;
    const float* W2; const float* b2; const float* W3; const float* b3;
    float* out;
    unsigned int* f1m; unsigned int* f2m;
    int* cntE1; int* cntD; int* cnt1; int* cnt2; int* bar;
    float* agg0; float* agg1; float* t2;
    int* e1src; int2* eD; int* list1; int* list2; int* pos1;
};

// Graph-capture-safe grid barrier: release add + relaxed poll + acquire fence.
// Requires all GRID blocks co-resident (capacity >= GRID, see launch config).
__device__ __forceinline__ void gsync(int* bar, int target) {
    __syncthreads();
    if (threadIdx.x == 0) {
        __threadfence();   // release: flush prior writes to device coherence point
        __hip_atomic_fetch_add(bar, 1, __ATOMIC_RELEASE, __HIP_MEMORY_SCOPE_AGENT);
        while (__hip_atomic_load(bar, __ATOMIC_RELAXED, __HIP_MEMORY_SCOPE_AGENT) < target)
            __builtin_amdgcn_s_sleep(4);
        __threadfence();   // acquire: invalidate L1/L2 so fresh data is visible
    }
    __syncthreads();
}

// One kernel, 4 grid barriers:
//   P1 edge pass (agg0 all-nodes + f1/e1src/list1/pos1)
//   P2 edge pass (eD=(src,slot) + f2/list2 + agg1-row zero)
//   P3 edge pass (inline layer-1->2 aggregation into agg1, wave-ballot)
//   P4 layer12 over list2    P5 fused tail on block 0
__global__ __launch_bounds__(TPB, 2) void gcn_k(Params p) {
    __shared__ __align__(16) float smem[MAXN1 * 64 + MAXN1];   // 49,920 B
    const int tid = threadIdx.x;
    const int gid = blockIdx.x * TPB + tid;
    const int T = GRID * TPB;

    // ---- P1: agg0[d] += x[s] (unconditional); dst==1 -> e1src + f1 + list1/pos1 ----
    {
        const int4* dst4 = (const int4*)p.dst;
        const int4* src4 = (const int4*)p.src;
        for (int t = gid; t < NE4; t += T) {
            int4 d4 = dst4[t]; int4 s4 = src4[t];
            int dv[4] = { d4.x, d4.y, d4.z, d4.w };
            int sv[4] = { s4.x, s4.y, s4.z, s4.w };
#pragma unroll
            for (int k = 0; k < 4; ++k) {
                atomicAdd(&p.agg0[dv[k]], p.x[sv[k]]);
                if (dv[k] == 1) {
                    p.e1src[atomicAdd(p.cntE1, 1)] = sv[k];
                    unsigned int bit = 1u << (sv[k] & 31);
                    unsigned int old = atomicOr(&p.f1m[sv[k] >> 5], bit);
                    if (!(old & bit)) {
                        int q = atomicAdd(p.cnt1, 1);
                        p.list1[q] = sv[k]; p.pos1[sv[k]] = q;
                    }
                }
            }
        }
    }
    gsync(p.bar, GRID);

    // ---- P2: f1[dst] -> eD=(src, pos1[dst]); f2 bit on src; first-setter: list2 + zero agg1 row ----
    {
        unsigned int* msk = (unsigned int*)smem;
        for (int k = tid; k < NMASKW; k += TPB) msk[k] = p.f1m[k];
        __syncthreads();
        const int4* dst4 = (const int4*)p.dst;
        for (int t = gid; t < NE4; t += T) {
            int4 d4 = dst4[t];
            int dv[4] = { d4.x, d4.y, d4.z, d4.w };
            int base = t * 4;
#pragma unroll
            for (int k = 0; k < 4; ++k) {
                if (mtest(msk, dv[k])) {
                    int ss = p.src[base + k];
                    unsigned int bit = 1u << (ss & 31);
                    unsigned int old = atomicOr(&p.f2m[ss >> 5], bit);
                    if (!(old & bit)) {
                        p.list2[atomicAdd(p.cnt2, 1)] = ss;
                        float4* z = (float4*)(p.agg1 + (size_t)ss * 64);
#pragma unroll
                        for (int r = 0; r < 16; ++r) z[r] = make_float4(0.f, 0.f, 0.f, 0.f);
                    }
                    p.eD[atomicAdd(p.cntD, 1)] = make_int2(ss, p.pos1[dv[k]]);
                }
            }
        }
    }
    gsync(p.bar, 2 * GRID);

    // ---- P3: f2[dst] -> agg1[dst][j] += lrelu(agg0[src]*W0[j]+b0[j]), wave-cooperative ----
    {
        unsigned int* msk = (unsigned int*)smem;
        for (int k = tid; k < NMASKW; k += TPB) msk[k] = p.f2m[k];
        __syncthreads();
        const int lane = tid & 63;
        const float w0 = p.W0[lane], bb0 = p.b0[lane];
        for (int t = gid; t < N_EDGES; t += T) {
            int d = p.dst[t];
            bool m = mtest(msk, d);
            int s = m ? p.src[t] : 0;
            unsigned long long bal = __ballot(m);
            while (bal) {
                int b = __builtin_ctzll(bal); bal &= bal - 1;
                int dd = __shfl(d, b, 64);
                int ss = __shfl(s, b, 64);
                float x0 = p.agg0[ss];                       // broadcast load
                atomicAdd(&p.agg1[(size_t)dd * 64 + lane], lrelu(x0 * w0 + bb0));
            }
        }
    }
    gsync(p.bar, 3 * GRID);

    // ---- P4: layer12 over list2 nodes: t2 = lrelu(agg1@W1+b1)@W2 ----
    {
        int c2 = *p.cnt2;
        float* rowA = smem;          // 64
        float* rowH = smem + 64;     // 128
        for (int idx = blockIdx.x; idx < c2; idx += GRID) {
            int i = p.list2[idx];
            __syncthreads();
            if (tid < 64) rowA[tid] = p.agg1[(size_t)i * 64 + tid];
            __syncthreads();
            if (tid < 128) {
                float acc = p.b1[tid];
#pragma unroll
                for (int k = 0; k < 64; ++k) acc += rowA[k] * p.W1[k * 128 + tid];
                rowH[tid] = lrelu(acc);
            }
            __syncthreads();
            if (tid < 64) {
                float a2 = 0.f;
#pragma unroll
                for (int k = 0; k < 128; ++k) a2 += rowH[k] * p.W2[k * 64 + tid];
                p.t2[(size_t)i * 64 + tid] = a2;
            }
        }
    }
    gsync(p.bar, 4 * GRID);

    // ---- P5: fused tail on block 0: layer-3 agg (LDS) + layer-4 + output ----
    if (blockIdx.x != 0) return;
    {
        float* acc = smem;                 // MAXN1*64
        float* t3s = smem + MAXN1 * 64;    // MAXN1
        int c1 = *p.cnt1, cD = *p.cntD, cE = *p.cntE1;
        for (int k = tid; k < c1 * 64; k += TPB) acc[k] = 0.f;
        __syncthreads();
        int j = tid & 63, widx = tid >> 6;     // 4 waves
        for (int idx = widx; idx < cD; idx += 4) {
            int2 e = p.eD[idx];
            atomicAdd(&acc[e.y * 64 + j], p.t2[(size_t)e.x * 64 + j]);
        }
        __syncthreads();
        for (int slot = widx; slot < c1; slot += 4) {
            float v = lrelu(acc[slot * 64 + j] + p.b2[j]) * p.W3[j];
            for (int off = 32; off > 0; off >>= 1) v += __shfl_down(v, off, 64);
            if (j == 0) t3s[slot] = v;
        }
        __syncthreads();
        if (tid < 64) {
            float ssum = 0.f;
            for (int k = tid; k < cE; k += 64) ssum += t3s[p.pos1[p.e1src[k]]];
            for (int off = 32; off > 0; off >>= 1) ssum += __shfl_down(ssum, off, 64);
            if (tid == 0) p.out[0] = lrelu(ssum + p.b3[0]);
        }
    }
}

extern "C" void kernel_launch(void* const* d_in, const int* in_sizes, int n_in,
                              void* d_out, int out_size, void* d_ws, size_t ws_size,
                              hipStream_t stream) {
    Params hp;
    hp.x   = (const float*)d_in[0];
    hp.src = (const int*)d_in[1];
    hp.dst = (const int*)d_in[2];
    hp.W0 = (const float*)d_in[3];  hp.b0 = (const float*)d_in[4];
    hp.W1 = (const float*)d_in[5];  hp.b1 = (const float*)d_in[6];
    hp.W2 = (const float*)d_in[7];  hp.b2 = (const float*)d_in[8];
    hp.W3 = (const float*)d_in[9];  hp.b3 = (const float*)d_in[10];
    hp.out = (float*)d_out;

    char* base = (char*)d_ws;
    size_t off = 0;
    auto take = [&](size_t bytes) { char* q = base + off; off += (bytes + 255) & ~(size_t)255; return q; };
    // ---- zeroed prefix (memset below) ----
    hp.f1m   = (unsigned int*)take(NMASKW * 4);
    hp.f2m   = (unsigned int*)take(NMASKW * 4);
    hp.cntE1 = (int*)take(4);
    hp.cntD  = (int*)take(4);
    hp.cnt1  = (int*)take(4);
    hp.cnt2  = (int*)take(4);
    hp.bar   = (int*)take(4);
    hp.agg0  = (float*)take((size_t)N_NODES * 4);
    size_t zero_bytes = off;
    // ---- uninitialized (rows zeroed on demand) ----
    hp.agg1  = (float*)take((size_t)N_NODES * 64 * 4);
    hp.t2    = (float*)take((size_t)N_NODES * 64 * 4);
    hp.e1src = (int*)take((size_t)N_NODES * 4);
    hp.eD    = (int2*)take((size_t)N_EDGES * 8);
    hp.list1 = (int*)take((size_t)N_NODES * 4);
    hp.list2 = (int*)take((size_t)N_NODES * 4);
    hp.pos1  = (int*)take((size_t)N_NODES * 4);

    hipMemsetAsync(base, 0, zero_bytes, stream);     // ~210 KB: masks+counters+bar+agg0
    gcn_k<<<GRID, TPB, 0, stream>>>(hp);
}

// Round 3
// 261.878 us; speedup vs baseline: 1.5534x; 1.5534x over previous
//
#include <hip/hip_runtime.h>

#define N_NODES 50000
#define N_EDGES 800000
#define NE4 (N_EDGES / 4)
#define NMASKW 1568          // ceil(50000/32)=1563, padded
#define MAXN1 192            // LDS accumulator rows (deg(node1)~16)
#define GRID 512             // co-resident: LDS allows 3 blocks/CU
#define TPB 256

// Cross-phase shared data goes through the coherence point (LLC) directly:
// relaxed agent-scope atomics => sc0/sc1 cache-bypassing ops, NO buffer_wbl2/buffer_inv.
#define AL(p)    __hip_atomic_load((p), __ATOMIC_RELAXED, __HIP_MEMORY_SCOPE_AGENT)
#define AS(p, v) __hip_atomic_store((p), (v), __ATOMIC_RELAXED, __HIP_MEMORY_SCOPE_AGENT)

__device__ __forceinline__ float lrelu(float v) { return v >= 0.f ? v : 0.01f * v; }
__device__ __forceinline__ bool mtest(const unsigned int* m, int i) {
    return (m[i >> 5] >> (i & 31)) & 1u;
}

struct Params {
    const float* x; const int* src; const int* dst;
    const float* W0; const float* b0; const float* W1; const float* b1;
    const float* W2; const float* b2; const float* W3; const float* b3;
    float* out;
    unsigned int* f1m; unsigned int* f2m;
    int* cntE1; int* cntD; int* cnt1; int* cnt2; int* bar;
    float* agg0; float* agg1; float* t2;
    int* e1src; int2* eD; int* list2; int* pos1;
};

// Lightweight grid barrier: __syncthreads drains each thread's vmcnt (so all the
// block's write-through stores/atomics are globally visible), then one relaxed
// agent-scope add + poll. No full-cache maintenance. Requires co-residency.
__device__ __forceinline__ void gsync(int* bar, int target) {
    __syncthreads();
    if (threadIdx.x == 0) {
        __hip_atomic_fetch_add(bar, 1, __ATOMIC_RELAXED, __HIP_MEMORY_SCOPE_AGENT);
        while (__hip_atomic_load(bar, __ATOMIC_RELAXED, __HIP_MEMORY_SCOPE_AGENT) < target)
            __builtin_amdgcn_s_sleep(1);
    }
    __syncthreads();
}

// One kernel, 4 grid barriers:
//   P1 edge pass (agg0 all-nodes + f1/e1src/pos1)
//   P2 edge pass (eD=(src,slot) + f2/list2 + agg1-row zero)
//   P3 edge pass (layer-1->2 aggregation into agg1, wave-ballot)
//   P4 layer12 over list2    P5 fused tail on block 0
__global__ __launch_bounds__(TPB, 2) void gcn_k(Params p) {
    __shared__ __align__(16) float smem[MAXN1 * 64 + MAXN1];   // 49,920 B
    const int tid = threadIdx.x;
    const int gid = blockIdx.x * TPB + tid;
    const int T = GRID * TPB;

    // ---- P1: agg0[d] += x[s] (unconditional); dst==1 -> e1src + f1 + pos1 ----
    {
        const int4* dst4 = (const int4*)p.dst;
        const int4* src4 = (const int4*)p.src;
        for (int t = gid; t < NE4; t += T) {
            int4 d4 = dst4[t]; int4 s4 = src4[t];
            int dv[4] = { d4.x, d4.y, d4.z, d4.w };
            int sv[4] = { s4.x, s4.y, s4.z, s4.w };
#pragma unroll
            for (int k = 0; k < 4; ++k) {
                atomicAdd(&p.agg0[dv[k]], p.x[sv[k]]);
                if (dv[k] == 1) {
                    AS(&p.e1src[atomicAdd(p.cntE1, 1)], sv[k]);
                    unsigned int bit = 1u << (sv[k] & 31);
                    unsigned int old = atomicOr(&p.f1m[sv[k] >> 5], bit);
                    if (!(old & bit)) {
                        int q = atomicAdd(p.cnt1, 1);
                        AS(&p.pos1[sv[k]], q);
                    }
                }
            }
        }
    }
    gsync(p.bar, GRID);

    // ---- P2: f1[dst] -> eD=(src, pos1[dst]); f2 bit on src; first-setter: list2 + zero agg1 row ----
    {
        unsigned int* msk = (unsigned int*)smem;
        for (int k = tid; k < NMASKW; k += TPB) msk[k] = AL(&p.f1m[k]);
        __syncthreads();
        const int4* dst4 = (const int4*)p.dst;
        for (int t = gid; t < NE4; t += T) {
            int4 d4 = dst4[t];
            int dv[4] = { d4.x, d4.y, d4.z, d4.w };
            int base = t * 4;
#pragma unroll
            for (int k = 0; k < 4; ++k) {
                if (mtest(msk, dv[k])) {
                    int ss = p.src[base + k];
                    unsigned int bit = 1u << (ss & 31);
                    unsigned int old = atomicOr(&p.f2m[ss >> 5], bit);
                    if (!(old & bit)) {
                        AS(&p.list2[atomicAdd(p.cnt2, 1)], ss);
                        float* z = p.agg1 + (size_t)ss * 64;
#pragma unroll
                        for (int r = 0; r < 64; ++r) AS(&z[r], 0.f);
                    }
                    unsigned long long ev =
                        (unsigned long long)(unsigned int)ss |
                        ((unsigned long long)(unsigned int)AL(&p.pos1[dv[k]]) << 32);
                    AS((unsigned long long*)&p.eD[atomicAdd(p.cntD, 1)], ev);
                }
            }
        }
    }
    gsync(p.bar, 2 * GRID);

    // ---- P3: f2[dst] -> agg1[dst][j] += lrelu(agg0[src]*W0[j]+b0[j]), wave-cooperative ----
    {
        unsigned int* msk = (unsigned int*)smem;
        for (int k = tid; k < NMASKW; k += TPB) msk[k] = AL(&p.f2m[k]);
        __syncthreads();
        const int lane = tid & 63;
        const float w0 = p.W0[lane], bb0 = p.b0[lane];
        for (int t = gid; t < N_EDGES; t += T) {
            int d = p.dst[t];
            bool m = mtest(msk, d);
            int s = m ? p.src[t] : 0;
            unsigned long long bal = __ballot(m);
            while (bal) {
                int b = __builtin_ctzll(bal); bal &= bal - 1;
                int dd = __shfl(d, b, 64);
                int ss = __shfl(s, b, 64);
                float x0 = AL(&p.agg0[ss]);                  // broadcast load from LLC
                atomicAdd(&p.agg1[(size_t)dd * 64 + lane], lrelu(x0 * w0 + bb0));
            }
        }
    }
    gsync(p.bar, 3 * GRID);

    // ---- P4: layer12 over list2 nodes: t2 = lrelu(agg1@W1+b1)@W2 ----
    {
        int c2 = AL(p.cnt2);
        float* rowA = smem;          // 64
        float* rowH = smem + 64;     // 128
        for (int idx = blockIdx.x; idx < c2; idx += GRID) {
            int i = AL(&p.list2[idx]);
            __syncthreads();
            if (tid < 64) rowA[tid] = AL(&p.agg1[(size_t)i * 64 + tid]);
            __syncthreads();
            if (tid < 128) {
                float acc = p.b1[tid];
#pragma unroll
                for (int k = 0; k < 64; ++k) acc += rowA[k] * p.W1[k * 128 + tid];
                rowH[tid] = lrelu(acc);
            }
            __syncthreads();
            if (tid < 64) {
                float a2 = 0.f;
#pragma unroll
                for (int k = 0; k < 128; ++k) a2 += rowH[k] * p.W2[k * 64 + tid];
                AS(&p.t2[(size_t)i * 64 + tid], a2);
            }
        }
    }
    gsync(p.bar, 4 * GRID);

    // ---- P5: fused tail on block 0: layer-3 agg (LDS) + layer-4 + output ----
    if (blockIdx.x != 0) return;
    {
        float* acc = smem;                 // MAXN1*64
        float* t3s = smem + MAXN1 * 64;    // MAXN1
        int c1 = AL(p.cnt1), cD = AL(p.cntD), cE = AL(p.cntE1);
        for (int k = tid; k < c1 * 64; k += TPB) acc[k] = 0.f;
        __syncthreads();
        int j = tid & 63, widx = tid >> 6;     // 4 waves
        for (int idx = widx; idx < cD; idx += 4) {
            unsigned long long ev = AL((unsigned long long*)&p.eD[idx]);
            int es = (int)(unsigned int)(ev & 0xffffffffull);
            int eslot = (int)(unsigned int)(ev >> 32);
            atomicAdd(&acc[eslot * 64 + j], AL(&p.t2[(size_t)es * 64 + j]));
        }
        __syncthreads();
        for (int slot = widx; slot < c1; slot += 4) {
            float v = lrelu(acc[slot * 64 + j] + p.b2[j]) * p.W3[j];
            for (int off = 32; off > 0; off >>= 1) v += __shfl_down(v, off, 64);
            if (j == 0) t3s[slot] = v;
        }
        __syncthreads();
        if (tid < 64) {
            float ssum = 0.f;
            for (int k = tid; k < cE; k += 64) ssum += t3s[AL(&p.pos1[AL(&p.e1src[k])])];
            for (int off = 32; off > 0; off >>= 1) ssum += __shfl_down(ssum, off, 64);
            if (tid == 0) p.out[0] = lrelu(ssum + p.b3[0]);
        }
    }
}

extern "C" void kernel_launch(void* const* d_in, const int* in_sizes, int n_in,
                              void* d_out, int out_size, void* d_ws, size_t ws_size,
                              hipStream_t stream) {
    Params hp;
    hp.x   = (const float*)d_in[0];
    hp.src = (const int*)d_in[1];
    hp.dst = (const int*)d_in[2];
    hp.W0 = (const float*)d_in[3];  hp.b0 = (const float*)d_in[4];
    hp.W1 = (const float*)d_in[5];  hp.b1 = (const float*)d_in[6];
    hp.W2 = (const float*)d_in[7];  hp.b2 = (const float*)d_in[8];
    hp.W3 = (const float*)d_in[9];  hp.b3 = (const float*)d_in[10];
    hp.out = (float*)d_out;

    char* base = (char*)d_ws;
    size_t off = 0;
    auto take = [&](size_t bytes) { char* q = base + off; off += (bytes + 255) & ~(size_t)255; return q; };
    // ---- zeroed prefix (memset below) ----
    hp.f1m   = (unsigned int*)take(NMASKW * 4);
    hp.f2m   = (unsigned int*)take(NMASKW * 4);
    hp.cntE1 = (int*)take(4);
    hp.cntD  = (int*)take(4);
    hp.cnt1  = (int*)take(4);
    hp.cnt2  = (int*)take(4);
    hp.bar   = (int*)take(4);
    hp.agg0  = (float*)take((size_t)N_NODES * 4);
    size_t zero_bytes = off;
    // ---- uninitialized (rows zeroed on demand) ----
    hp.agg1  = (float*)take((size_t)N_NODES * 64 * 4);
    hp.t2    = (float*)take((size_t)N_NODES * 64 * 4);
    hp.e1src = (int*)take((size_t)N_NODES * 4);
    hp.eD    = (int2*)take((size_t)N_EDGES * 8);
    hp.list2 = (int*)take((size_t)N_NODES * 4);
    hp.pos1  = (int*)take((size_t)N_NODES * 4);

    hipMemsetAsync(base, 0, zero_bytes, stream);     // ~210 KB: masks+counters+bar+agg0
    gcn_k<<<GRID, TPB, 0, stream>>>(hp);
}